// Round 5
// baseline (22292.900 us; speedup 1.0000x reference)
//
#include <hip/hip_runtime.h>
#include <math.h>

#define T_ 512

// fp32 fast nonlinearities (reference path is fp32 sigmoid/tanh).
__device__ __forceinline__ float sigf(float x) {
  return __builtin_amdgcn_rcpf(1.0f + __expf(-x));
}
__device__ __forceinline__ float tanhf_(float x) {
  float e = __expf(x + x);                    // inf for large x -> t=1; 0 -> t=-1
  return 1.0f - 2.0f * __builtin_amdgcn_rcpf(e + 1.0f);
}

// Coherent (agent-scope, cache-bypassing) 4-byte load/store for fp32 h exchange.
__device__ __forceinline__ float hloadf(const float* p) {
  unsigned u = __hip_atomic_load((const unsigned*)p,
                                 __ATOMIC_RELAXED, __HIP_MEMORY_SCOPE_AGENT);
  return __builtin_bit_cast(float, u);
}
__device__ __forceinline__ void hstoref(float* p, float v) {
  __hip_atomic_store((unsigned*)p, __builtin_bit_cast(unsigned, v),
                     __ATOMIC_RELAXED, __HIP_MEMORY_SCOPE_AGENT);
}

// A row kc at kc*16 + 4*(kc>>5): 16 fp32 rows (64B), 16B-aligned, +4-float
// stagger per 32-kc block -> the 16 in-wave k-team b128 bases sit at banks
// {4kt%32}: kt and kt+8 share a 4-bank window = 2-way = free; og lanes share
// addresses (broadcast).
__device__ __forceinline__ int aoff16(int kc) { return (kc << 4) + ((kc >> 5) << 2); }

// Grid 256 = 16 groups x 16 blocks. Group g owns batch rows [16g,16g+16);
// block w owns h-cols [16w,16w+16) of BOTH layers. KEY CHANGE vs R4: per-block
// weight slice is now 256 KB = 512 B/thread = 128 VGPRs -> weights live in
// registers permanently (float4 wc[32], loaded once). Steady-state GEMM does
// ZERO global loads (R4 re-streamed 512 KB/block/phase from L2 = ~9.4k cyc/CU).
// GEMM: wave = (layer, gate); lane = (kt 16, og 4); K=32/lane; acc[4 cols][16 rows].
// Reduce: 4-round recursive halving over kt (60 shuffles), lane ends with row kt.
__global__ __launch_bounds__(512, 1) void lstm2_head(
    const float* __restrict__ x, const float* __restrict__ W1,
    const float* __restrict__ b1, const float* __restrict__ W2,
    const float* __restrict__ b2, const float* __restrict__ Wo,
    const float* __restrict__ bo, float* __restrict__ out,
    unsigned char* __restrict__ ws)
{
  __shared__ float Alds[12384];  // [kc 768][r 16] + stagger (49.5 KB)
  __shared__ float zbuf[2176];   // [(half,gate,r) 128][16 +1 pad] (8.7 KB)

  const int tid = threadIdx.x;
  const int g  = blockIdx.x >> 4;    // 0..15
  const int w  = blockIdx.x & 15;    // 0..15
  const int rb0 = g << 4;

  unsigned* bar = (unsigned*)ws + (g << 4);            // 64B-spaced counters
  float* hbase = (float*)(ws + 4096);
  float* h1g = hbase + (size_t)g * 8192;               // [2 slots][16 r][256] fp32
  float* h2g = hbase + 131072 + (size_t)g * 8192;

  // Zero both slots of both h arrays (redundant across the group's blocks, benign).
  for (int i = tid; i < 8192; i += 512) { hstoref(h1g + i, 0.0f); hstoref(h2g + i, 0.0f); }

  // group barrier #0 (16 blocks/group)
  __builtin_amdgcn_s_waitcnt(0);
  __syncthreads();
  if (tid == 0) {
    __hip_atomic_fetch_add(bar, 1u, __ATOMIC_RELAXED, __HIP_MEMORY_SCOPE_AGENT);
    while (__hip_atomic_load(bar, __ATOMIC_RELAXED, __HIP_MEMORY_SCOPE_AGENT) < 16u) {}
    __asm__ volatile("" ::: "memory");
  }
  __syncthreads();

  // ---- GEMM mapping ----
  const int lane = tid & 63;
  const int wvid = tid >> 6;               // wave 0..7
  const int half = wvid >> 2;              // 0 = layer1, 1 = layer2
  const int gate = wvid & 3;               // i,j,f,o
  const int kt   = lane >> 2;              // in-wave k-team 0..15 (K=32 each)
  const int og   = lane & 3;               // col-quad within the 16-col slice
  const bool q5 = (lane & 32) != 0;        // kt bit3
  const bool q4 = (lane & 16) != 0;        // kt bit2
  const bool q3 = (lane & 8)  != 0;        // kt bit1
  const bool q2 = (lane & 4)  != 0;        // kt bit0
  const float* Wp = half ? W2 : W1;
  const int colb = (gate << 8) + (w << 4) + (og << 2);

  // ---- register-resident weights: 32 float4 = 128 VGPRs, loaded ONCE ----
  float4 wc[32];
  #pragma unroll
  for (int s = 0; s < 32; ++s)
    wc[s] = *(const float4*)(Wp + (size_t)((kt << 5) + s) * 1024 + colb);

  const int abase = aoff16((half << 8) + (kt << 5));   // + s*16 per k-step
  const int zrow  = (((half << 2) + gate) << 4) + kt;

  // ---- staging mapping: thread = (row sr 16, 8-col group skg 32) ----
  const int sr  = tid & 15;
  const int skg = tid >> 4;
  const int sc0 = skg << 3;

  // ---- update mapping: one cell per thread (512 = 2L x 16r x 16c) ----
  const int L  = tid >> 8;
  const int ur = (tid >> 4) & 15;
  const int uc = tid & 15;
  const float* ubb = L ? b2 : b1;
  const int ucol = (w << 4) + uc;
  const float ub_i = ubb[ucol];
  const float ub_j = ubb[256 + ucol];
  const float ub_f = ubb[512 + ucol] + 1.0f;   // forget bias folded
  const float ub_o = ubb[768 + ucol];
  double cst = 0.0;

  const bool headblk = (w == 0);

  // head: wave v owns rows 2v,2v+1; lane owns h2-cols {lane,64+,128+,192+}.
  // Wo/bo reloaded per call (runs in barrier shadow; saves 30 persistent regs).
  auto do_head = [&](int t3) {
    float wo_r[4][6];
    float bo_r[6];
    #pragma unroll
    for (int q = 0; q < 4; ++q)
      #pragma unroll
      for (int c = 0; c < 6; ++c) wo_r[q][c] = Wo[(lane + (q << 6)) * 6 + c];
    #pragma unroll
    for (int c = 0; c < 6; ++c) bo_r[c] = bo[c];
    #pragma unroll
    for (int rr = 0; rr < 2; ++rr) {
      const int r = (wvid << 1) + rr;
      float pr[6] = {0, 0, 0, 0, 0, 0};
      #pragma unroll
      for (int q = 0; q < 4; ++q) {
        float hv = Alds[aoff16(512 + lane + (q << 6)) + r];
        #pragma unroll
        for (int c = 0; c < 6; ++c) pr[c] = fmaf(hv, wo_r[q][c], pr[c]);
      }
      #pragma unroll
      for (int off = 1; off <= 32; off <<= 1)
        #pragma unroll
        for (int c = 0; c < 6; ++c) pr[c] += __shfl_xor(pr[c], off, 64);
      if (lane == 0) {
        size_t orow = (((size_t)(rb0 + r)) << 9) + (size_t)t3;   // b*T + t
        #pragma unroll
        for (int c = 0; c < 6; ++c) {
          float lg = pr[c] + bo_r[c];
          out[orow * 6 + c] = lg;
          float pd = (lg > 0.0f) ? 1.0f : 0.0f;      // 0.5 < sigmoid <=> lg > 0
          out[(size_t)786432 + orow * 6 + c] = pd;   // condition
          out[(size_t)1572864 + orow * 6 + c] = pd;  // prediction
        }
      }
    }
  };

  // ---- prologue stage for phase 0: x(0), h1(-1)=0 (slot1), h2(-2)=0 (slot0) ----
  {
    const float* xb = x + (size_t)(rb0 + sr) * (T_ * 256) + sc0;   // t=0
    float sv[8];
    #pragma unroll
    for (int j = 0; j < 8; ++j) sv[j] = xb[j];
    #pragma unroll
    for (int j = 0; j < 8; ++j) Alds[aoff16(sc0 + j) + sr] = sv[j];
    const float* h1p = h1g + 4096;
    const float* h2p = h2g;
    float hv[16];
    #pragma unroll
    for (int j = 0; j < 8; ++j) hv[j]     = hloadf(h1p + (sr << 8) + sc0 + j);
    #pragma unroll
    for (int j = 0; j < 8; ++j) hv[8 + j] = hloadf(h2p + (sr << 8) + sc0 + j);
    #pragma unroll
    for (int j = 0; j < 8; ++j) Alds[aoff16(256 + sc0 + j) + sr] = hv[j];
    #pragma unroll
    for (int j = 0; j < 8; ++j) Alds[aoff16(512 + sc0 + j) + sr] = hv[8 + j];
  }
  __syncthreads();

  // Phase p: layer1(t=p), layer2(t=p-1), head(t=p-2).
  #pragma unroll 1
  for (int p = 0; p <= T_ + 1; ++p) {
    // ---- GEMM: all weights in regs; per k-step 4x ds_read_b128 (16 rows) ----
    float acc[4][16];
    #pragma unroll
    for (int c = 0; c < 4; ++c)
      #pragma unroll
      for (int r = 0; r < 16; ++r) acc[c][r] = 0.0f;
    {
      const float* ap = Alds + abase;
      #pragma unroll
      for (int s = 0; s < 32; ++s) {
        const float* as = ap + (s << 4);
        float4 a0 = *(const float4*)(as);
        float4 a1 = *(const float4*)(as + 4);
        float4 a2 = *(const float4*)(as + 8);
        float4 a3 = *(const float4*)(as + 12);
        float a[16] = {a0.x, a0.y, a0.z, a0.w, a1.x, a1.y, a1.z, a1.w,
                       a2.x, a2.y, a2.z, a2.w, a3.x, a3.y, a3.z, a3.w};
        #pragma unroll
        for (int r = 0; r < 16; ++r) {
          acc[0][r] = fmaf(a[r], wc[s].x, acc[0][r]);
          acc[1][r] = fmaf(a[r], wc[s].y, acc[1][r]);
          acc[2][r] = fmaf(a[r], wc[s].z, acc[2][r]);
          acc[3][r] = fmaf(a[r], wc[s].w, acc[3][r]);
        }
      }
    }

    // ---- reduce-scatter over 16 k-teams: 4 rounds of recursive halving.
    // Round: keep own half, send the partner's half, add received. After 4
    // rounds lane (kt,og) holds the full sum for row kt, cols og*4..+4.
    float t1[4][8];
    #pragma unroll
    for (int c = 0; c < 4; ++c)
      #pragma unroll
      for (int q = 0; q < 8; ++q) {
        float send = q5 ? acc[c][q] : acc[c][q + 8];
        float keep = q5 ? acc[c][q + 8] : acc[c][q];
        t1[c][q] = keep + __shfl_xor(send, 32, 64);
      }
    float t2[4][4];
    #pragma unroll
    for (int c = 0; c < 4; ++c)
      #pragma unroll
      for (int q = 0; q < 4; ++q) {
        float send = q4 ? t1[c][q] : t1[c][q + 4];
        float keep = q4 ? t1[c][q + 4] : t1[c][q];
        t2[c][q] = keep + __shfl_xor(send, 16, 64);
      }
    float t3[4][2];
    #pragma unroll
    for (int c = 0; c < 4; ++c)
      #pragma unroll
      for (int q = 0; q < 2; ++q) {
        float send = q3 ? t2[c][q] : t2[c][q + 2];
        float keep = q3 ? t2[c][q + 2] : t2[c][q];
        t3[c][q] = keep + __shfl_xor(send, 8, 64);
      }
    #pragma unroll
    for (int c = 0; c < 4; ++c) {
      float send = q2 ? t3[c][0] : t3[c][1];
      float keep = q2 ? t3[c][1] : t3[c][0];
      float zv = keep + __shfl_xor(send, 4, 64);
      zbuf[zrow * 17 + (og << 2) + c] = zv;
    }
    __syncthreads();   // #1: z ready

    // ---- Cell update: fp32 gates (v_exp_f32), fp64 c-state accumulate ----
    {
      const bool uact = L ? (p >= 1 && p <= T_) : (p < T_);
      if (uact) {
        const float* za = zbuf + ((L << 6) + ur) * 17 + uc;   // gate stride 272
        float si = sigf(za[0]   + ub_i);
        float tj = tanhf_(za[272] + ub_j);
        float sf = sigf(za[544] + ub_f);
        float so = sigf(za[816] + ub_o);
        cst = cst * (double)sf + (double)(si * tj);
        float hv = tanhf_((float)cst) * so;
        float* hd = L ? (h2g + (((p + 1) & 1) << 12)) : (h1g + ((p & 1) << 12));
        hstoref(hd + (ur << 8) + ucol, hv);
      }
    }

    if (p <= T_) {
      __builtin_amdgcn_s_waitcnt(0);
      __syncthreads();   // #2: all waves' h stores drained
      if (tid == 0)
        __hip_atomic_fetch_add(bar, 1u, __ATOMIC_RELAXED, __HIP_MEMORY_SCOPE_AGENT);

      // ---- barrier shadow: x(p+1) prefetch, head(p-2), x LDS writes ----
      const int xp1 = (p + 1 < T_) ? (p + 1) : (T_ - 1);
      const float* xb = x + (size_t)(rb0 + sr) * (T_ * 256) + (size_t)xp1 * 256 + sc0;
      float xv[8];
      #pragma unroll
      for (int j = 0; j < 8; ++j) xv[j] = xb[j];

      // head reads Alds [512,768) = h2(p-2): untouched until after sync #3
      if (headblk && p >= 2) do_head(p - 2);

      #pragma unroll
      for (int j = 0; j < 8; ++j) Alds[aoff16(sc0 + j) + sr] = xv[j];

      if (tid == 0) {
        const unsigned target = ((unsigned)(p + 2)) << 4;
        while (__hip_atomic_load(bar, __ATOMIC_RELAXED, __HIP_MEMORY_SCOPE_AGENT) < target) {}
        __asm__ volatile("" ::: "memory");
      }
      __syncthreads();   // #3: group h published

      // ---- stage h1(p), h2(p-1) for phase p+1 ----
      const float* h1p = h1g + ((p & 1) << 12);
      const float* h2p = h2g + (((p + 1) & 1) << 12);
      float hv[16];
      #pragma unroll
      for (int j = 0; j < 8; ++j) hv[j]     = hloadf(h1p + (sr << 8) + sc0 + j);
      #pragma unroll
      for (int j = 0; j < 8; ++j) hv[8 + j] = hloadf(h2p + (sr << 8) + sc0 + j);
      #pragma unroll
      for (int j = 0; j < 8; ++j) Alds[aoff16(256 + sc0 + j) + sr] = hv[j];
      #pragma unroll
      for (int j = 0; j < 8; ++j) Alds[aoff16(512 + sc0 + j) + sr] = hv[8 + j];
      __syncthreads();   // #4: A staged for next phase
    } else {
      // final phase: emit last head (t3 = T_-1), no barrier/stage needed
      if (headblk) do_head(p - 2);
    }
  }
}

extern "C" void kernel_launch(void* const* d_in, const int* in_sizes, int n_in,
                              void* d_out, int out_size, void* d_ws, size_t ws_size,
                              hipStream_t stream) {
  const float* x  = (const float*)d_in[0];
  const float* W1 = (const float*)d_in[1];
  const float* b1 = (const float*)d_in[2];
  const float* W2 = (const float*)d_in[3];
  const float* b2 = (const float*)d_in[4];
  const float* Wo = (const float*)d_in[5];
  const float* bo = (const float*)d_in[6];
  float* out = (float*)d_out;
  unsigned char* ws = (unsigned char*)d_ws;

  // Zero barrier counters (first 4 KB of ws); part of the captured graph.
  hipMemsetAsync(d_ws, 0, 4096, stream);

  lstm2_head<<<dim3(256), dim3(512), 0, stream>>>(x, W1, b1, W2, b2, Wo, bo, out, ws);
}

// Round 6
// 10405.202 us; speedup vs baseline: 2.1425x; 2.1425x over previous
//
#include <hip/hip_runtime.h>
#include <math.h>

#define T_ 512

// fp32 fast nonlinearities (reference path is fp32 sigmoid/tanh).
__device__ __forceinline__ float sigf(float x) {
  return __builtin_amdgcn_rcpf(1.0f + __expf(-x));
}
__device__ __forceinline__ float tanhf_(float x) {
  float e = __expf(x + x);                    // inf for large x -> t=1; 0 -> t=-1
  return 1.0f - 2.0f * __builtin_amdgcn_rcpf(e + 1.0f);
}

// Coherent (agent-scope, cache-bypassing) 4-byte load/store for fp32 h exchange.
__device__ __forceinline__ float hloadf(const float* p) {
  unsigned u = __hip_atomic_load((const unsigned*)p,
                                 __ATOMIC_RELAXED, __HIP_MEMORY_SCOPE_AGENT);
  return __builtin_bit_cast(float, u);
}
__device__ __forceinline__ void hstoref(float* p, float v) {
  __hip_atomic_store((unsigned*)p, __builtin_bit_cast(unsigned, v),
                     __ATOMIC_RELAXED, __HIP_MEMORY_SCOPE_AGENT);
}

// A row kc at kc*8 + 4*(kc>>5): 8 fp32 rows (32B), 16B-aligned, +4-float
// stagger per 32-kc block. k-team windows are 32-kc aligned so the stagger is
// constant inside a team's window; team bases sit at banks {4*kt mod 32} ->
// two teams per 4-bank window = 2-way = free; og lanes share addresses
// (broadcast).
__device__ __forceinline__ int aoff8(int kc) { return (kc << 3) + ((kc >> 5) << 2); }

// Grid 512 = 32 groups x 16 blocks, 2 blocks/CU (R6 change: 4 waves/SIMD, and
// the two co-resident blocks are in DIFFERENT groups with independent
// barriers, so one block's GEMM hides the other's serial tail).
// Group g owns batch rows [8g, 8g+8); block w owns h-cols [16w,16w+16) of both
// layers. XCD = blockIdx%8 = w%8: each XCD's L2 caches 2 col-slices (512 KB).
// VGPR reality (R1/R5): compiler pins 128 regs; sized to fit (acc 32 + buf 64).
// GEMM: wave = (layer, gate); lane = (kt 16, og 4); K=32/team; acc[4][8].
// Reduce: recursive halving over kt bits (rows: 3 rounds, cols: 1), 30 shuffles.
__global__ __launch_bounds__(512, 2) void lstm2_head(
    const float* __restrict__ x, const float* __restrict__ W1,
    const float* __restrict__ b1, const float* __restrict__ W2,
    const float* __restrict__ b2, const float* __restrict__ Wo,
    const float* __restrict__ bo, float* __restrict__ out,
    unsigned char* __restrict__ ws)
{
  __shared__ float Alds[6240];   // [kc 768][r 8] stride 8 + stagger (25 KB)
  __shared__ float zbuf[1088];   // [(half,gate,r) 64][16 +1 pad] (4.4 KB)

  const int tid = threadIdx.x;
  const int g  = blockIdx.x >> 4;    // 0..31
  const int w  = blockIdx.x & 15;    // 0..15
  const int rb0 = g << 3;

  unsigned* bar = (unsigned*)ws + (g << 4);            // 64B-spaced counters
  float* hbase = (float*)(ws + 4096);
  float* h1g = hbase + (size_t)g * 4096;               // [2 slots][8 r][256] fp32
  float* h2g = hbase + 131072 + (size_t)g * 4096;

  // Zero both slots of both h arrays (redundant across the group's blocks, benign).
  for (int i = tid; i < 4096; i += 512) { hstoref(h1g + i, 0.0f); hstoref(h2g + i, 0.0f); }

  // group barrier #0 (16 blocks/group)
  __builtin_amdgcn_s_waitcnt(0);
  __syncthreads();
  if (tid == 0) {
    __hip_atomic_fetch_add(bar, 1u, __ATOMIC_RELAXED, __HIP_MEMORY_SCOPE_AGENT);
    while (__hip_atomic_load(bar, __ATOMIC_RELAXED, __HIP_MEMORY_SCOPE_AGENT) < 16u) {}
    __asm__ volatile("" ::: "memory");
  }
  __syncthreads();

  // ---- GEMM mapping ----
  const int lane = tid & 63;
  const int wvid = tid >> 6;               // wave 0..7
  const int half = wvid >> 2;              // 0 = layer1, 1 = layer2
  const int gate = wvid & 3;               // i,j,f,o
  const int kt   = lane >> 2;              // in-wave k-team 0..15 (K=32 each)
  const int og   = lane & 3;               // col-quad within the 16-col slice
  const bool b5 = (lane & 32) != 0;        // kt bit3
  const bool b4 = (lane & 16) != 0;        // kt bit2
  const bool b3 = (lane & 8)  != 0;        // kt bit1
  const bool b2b = (lane & 4) != 0;        // kt bit0
  const float* Wp = half ? W2 : W1;
  const float* wbase = Wp + (size_t)(kt << 5) * 1024
                          + (gate << 8) + (w << 4) + (og << 2);
  const int abase = aoff8((half << 8) + (kt << 5));
  const int zrowb = ((half << 2) + gate) << 3;

  // ---- staging mapping ----
  const int sr  = tid & 7;                 // A-row
  const int skc = tid >> 3;                // 0..63

  // ---- update mapping: 256 cells over threads with (tid&255)<128 ----
  const int L  = tid >> 8;
  const int rem = tid & 255;
  const int ur = (rem >> 4) & 7;
  const int uc = rem & 15;
  const bool ucell = rem < 128;
  const float* ubb = L ? b2 : b1;
  const int ucol = (w << 4) + uc;
  const float ub_i = ubb[ucol];
  const float ub_j = ubb[256 + ucol];
  const float ub_f = ubb[512 + ucol] + 1.0f;   // forget bias folded
  const float ub_o = ubb[768 + ucol];
  double cst = 0.0;

  const bool headblk = (w == 0);

  // head: wave v owns row v; lane owns h2-cols {lane,64+,128+,192+}.
  // Wo/bo reloaded per call (runs in barrier shadow; saves persistent regs).
  auto do_head = [&](int t3) {
    float wo_r[4][6];
    float bo_r[6];
    #pragma unroll
    for (int q = 0; q < 4; ++q)
      #pragma unroll
      for (int c = 0; c < 6; ++c) wo_r[q][c] = Wo[(lane + (q << 6)) * 6 + c];
    #pragma unroll
    for (int c = 0; c < 6; ++c) bo_r[c] = bo[c];
    float pr[6] = {0, 0, 0, 0, 0, 0};
    #pragma unroll
    for (int q = 0; q < 4; ++q) {
      float hv = Alds[aoff8(512 + lane + (q << 6)) + wvid];
      #pragma unroll
      for (int c = 0; c < 6; ++c) pr[c] = fmaf(hv, wo_r[q][c], pr[c]);
    }
    #pragma unroll
    for (int off = 1; off <= 32; off <<= 1)
      #pragma unroll
      for (int c = 0; c < 6; ++c) pr[c] += __shfl_xor(pr[c], off, 64);
    if (lane == 0) {
      size_t orow = (((size_t)(rb0 + wvid)) << 9) + (size_t)t3;   // b*T + t
      #pragma unroll
      for (int c = 0; c < 6; ++c) {
        float lg = pr[c] + bo_r[c];
        out[orow * 6 + c] = lg;
        float pd = (lg > 0.0f) ? 1.0f : 0.0f;      // 0.5 < sigmoid <=> lg > 0
        out[(size_t)786432 + orow * 6 + c] = pd;   // condition
        out[(size_t)1572864 + orow * 6 + c] = pd;  // prediction
      }
    }
  };

  // ---- prologue stage for phase 0: x(0), h1(-1)=0 (slot1), h2(-2)=0 (slot0) ----
  {
    const float* xb = x + (size_t)(rb0 + sr) * (T_ * 256) + skc;   // t=0
    float sv[12];
    #pragma unroll
    for (int v = 0; v < 4; ++v) sv[v] = xb[v << 6];
    const float* h1p = h1g + 2048;   // slot 1 (zeroed)
    const float* h2p = h2g;          // slot 0 (zeroed)
    #pragma unroll
    for (int v = 0; v < 4; ++v) sv[4 + v] = hloadf(h1p + (sr << 8) + skc + (v << 6));
    #pragma unroll
    for (int v = 0; v < 4; ++v) sv[8 + v] = hloadf(h2p + (sr << 8) + skc + (v << 6));
    #pragma unroll
    for (int v = 0; v < 12; ++v) Alds[aoff8((v << 6) + skc) + sr] = sv[v];
  }
  __syncthreads();

  // Weights are phase-invariant: first 8-k batch is loop-carried in wva and
  // reloaded each phase inside the barrier shadow (L2 latency hidden).
  float4 wva[8];
  #pragma unroll
  for (int j = 0; j < 8; ++j) wva[j] = *(const float4*)(wbase + (size_t)j * 1024);

  // Phase p: layer1(t=p), layer2(t=p-1), head(t=p-2).
  #pragma unroll 1
  for (int p = 0; p <= T_ + 1; ++p) {
    // ---- GEMM: lane covers 4 gate-cols x 8 rows over k in [32kt, 32kt+32).
    float acc[4][8];
    #pragma unroll
    for (int c = 0; c < 4; ++c)
      #pragma unroll
      for (int r = 0; r < 8; ++r) acc[c][r] = 0.0f;
    {
      const float* ap = Alds + abase;
      float4 wvb[8];
      #pragma unroll 1
      for (int sg = 0; sg < 2; ++sg) {
        const int s0 = sg << 4;
        #pragma unroll
        for (int j = 0; j < 8; ++j)
          wvb[j] = *(const float4*)(wbase + (size_t)(s0 + 8 + j) * 1024);
        #pragma unroll
        for (int j = 0; j < 8; ++j) {
          const float* apj = ap + ((s0 + j) << 3);
          float4 a0 = *(const float4*)(apj);
          float4 a1 = *(const float4*)(apj + 4);
          float a[8] = {a0.x, a0.y, a0.z, a0.w, a1.x, a1.y, a1.z, a1.w};
          #pragma unroll
          for (int r = 0; r < 8; ++r) {
            acc[0][r] = fmaf(a[r], wva[j].x, acc[0][r]);
            acc[1][r] = fmaf(a[r], wva[j].y, acc[1][r]);
            acc[2][r] = fmaf(a[r], wva[j].z, acc[2][r]);
            acc[3][r] = fmaf(a[r], wva[j].w, acc[3][r]);
          }
        }
        if (sg < 1) {
          #pragma unroll
          for (int j = 0; j < 8; ++j)
            wva[j] = *(const float4*)(wbase + (size_t)(s0 + 16 + j) * 1024);
        }
        #pragma unroll
        for (int j = 0; j < 8; ++j) {
          const float* apj = ap + ((s0 + 8 + j) << 3);
          float4 a0 = *(const float4*)(apj);
          float4 a1 = *(const float4*)(apj + 4);
          float a[8] = {a0.x, a0.y, a0.z, a0.w, a1.x, a1.y, a1.z, a1.w};
          #pragma unroll
          for (int r = 0; r < 8; ++r) {
            acc[0][r] = fmaf(a[r], wvb[j].x, acc[0][r]);
            acc[1][r] = fmaf(a[r], wvb[j].y, acc[1][r]);
            acc[2][r] = fmaf(a[r], wvb[j].z, acc[2][r]);
            acc[3][r] = fmaf(a[r], wvb[j].w, acc[3][r]);
          }
        }
      }
    }

    // ---- reduce-scatter over 16 k-teams (recursive halving, 30 shuffles).
    // Rounds on kt bits 3,2,1 scatter the 8 rows; the round on kt bit0
    // scatters the 4 cols in pairs. Lane ends with row kt>>1, col pair
    // og*4 + ktbit0*2, summed over the full K=512.
    float t1[4][4];
    #pragma unroll
    for (int c = 0; c < 4; ++c)
      #pragma unroll
      for (int q = 0; q < 4; ++q) {
        float send = b5 ? acc[c][q] : acc[c][q + 4];
        float keep = b5 ? acc[c][q + 4] : acc[c][q];
        t1[c][q] = keep + __shfl_xor(send, 32, 64);
      }
    float t2[4][2];
    #pragma unroll
    for (int c = 0; c < 4; ++c)
      #pragma unroll
      for (int q = 0; q < 2; ++q) {
        float send = b4 ? t1[c][q] : t1[c][q + 2];
        float keep = b4 ? t1[c][q + 2] : t1[c][q];
        t2[c][q] = keep + __shfl_xor(send, 16, 64);
      }
    float t3v[4];
    #pragma unroll
    for (int c = 0; c < 4; ++c) {
      float send = b3 ? t2[c][0] : t2[c][1];
      float keep = b3 ? t2[c][1] : t2[c][0];
      t3v[c] = keep + __shfl_xor(send, 8, 64);
    }
    {
      float send0 = b2b ? t3v[0] : t3v[2];
      float send1 = b2b ? t3v[1] : t3v[3];
      float keep0 = b2b ? t3v[2] : t3v[0];
      float keep1 = b2b ? t3v[3] : t3v[1];
      float z0 = keep0 + __shfl_xor(send0, 4, 64);
      float z1 = keep1 + __shfl_xor(send1, 4, 64);
      const int zi = (zrowb + (kt >> 1)) * 17 + (og << 2) + ((kt & 1) << 1);
      zbuf[zi]     = z0;
      zbuf[zi + 1] = z1;
    }
    __syncthreads();   // #1: z ready

    // ---- Cell update: fp32 gates (v_exp_f32), fp64 c-state accumulate ----
    {
      const bool uact = ucell && (L ? (p >= 1 && p <= T_) : (p < T_));
      if (uact) {
        const float* za = zbuf + ((L << 5) + ur) * 17 + uc;   // gate stride 136
        float si = sigf(za[0]   + ub_i);
        float tj = tanhf_(za[136] + ub_j);
        float sf = sigf(za[272] + ub_f);
        float so = sigf(za[408] + ub_o);
        cst = cst * (double)sf + (double)(si * tj);
        float hv = tanhf_((float)cst) * so;
        float* hd = L ? (h2g + (((p + 1) & 1) << 11)) : (h1g + ((p & 1) << 11));
        hstoref(hd + (ur << 8) + ucol, hv);
      }
    }

    if (p <= T_) {
      // head BEFORE the drain: w0's head work hides its own store latency.
      if (headblk && p >= 2) do_head(p - 2);

      __builtin_amdgcn_s_waitcnt(0);
      __syncthreads();   // #2: all waves' h stores drained
      if (tid == 0)
        __hip_atomic_fetch_add(bar, 1u, __ATOMIC_RELAXED, __HIP_MEMORY_SCOPE_AGENT);

      // ---- barrier shadow: x(p+1) prefetch + next-phase weight batch ----
      const int xp1 = (p + 1 < T_) ? (p + 1) : (T_ - 1);
      const float* xb = x + (size_t)(rb0 + sr) * (T_ * 256) + (size_t)xp1 * 256 + skc;
      float xv[4];
      #pragma unroll
      for (int v = 0; v < 4; ++v) xv[v] = xb[v << 6];
      #pragma unroll
      for (int v = 0; v < 4; ++v) Alds[aoff8((v << 6) + skc) + sr] = xv[v];

      #pragma unroll
      for (int j = 0; j < 8; ++j) wva[j] = *(const float4*)(wbase + (size_t)j * 1024);

      if (tid == 0) {
        const unsigned target = ((unsigned)(p + 2)) << 4;
        while (__hip_atomic_load(bar, __ATOMIC_RELAXED, __HIP_MEMORY_SCOPE_AGENT) < target) {}
        __asm__ volatile("" ::: "memory");
      }
      __syncthreads();   // #3: group h published

      // ---- stage h1(p), h2(p-1) for phase p+1 ----
      const float* h1p = h1g + ((p & 1) << 11);
      const float* h2p = h2g + (((p + 1) & 1) << 11);
      float hv8[8];
      #pragma unroll
      for (int v = 0; v < 4; ++v) hv8[v] = hloadf(h1p + (sr << 8) + skc + (v << 6));
      #pragma unroll
      for (int v = 0; v < 4; ++v) hv8[4 + v] = hloadf(h2p + (sr << 8) + skc + (v << 6));
      #pragma unroll
      for (int v = 0; v < 8; ++v) Alds[aoff8(256 + (v << 6) + skc) + sr] = hv8[v];
      __syncthreads();   // #4: A staged for next phase
    } else {
      // final phase: emit last head (t3 = T_-1), no barrier/stage needed
      if (headblk) do_head(p - 2);
    }
  }
}

extern "C" void kernel_launch(void* const* d_in, const int* in_sizes, int n_in,
                              void* d_out, int out_size, void* d_ws, size_t ws_size,
                              hipStream_t stream) {
  const float* x  = (const float*)d_in[0];
  const float* W1 = (const float*)d_in[1];
  const float* b1 = (const float*)d_in[2];
  const float* W2 = (const float*)d_in[3];
  const float* b2 = (const float*)d_in[4];
  const float* Wo = (const float*)d_in[5];
  const float* bo = (const float*)d_in[6];
  float* out = (float*)d_out;
  unsigned char* ws = (unsigned char*)d_ws;

  // Zero barrier counters (first 4 KB of ws); part of the captured graph.
  hipMemsetAsync(d_ws, 0, 4096, stream);

  lstm2_head<<<dim3(512), dim3(512), 0, stream>>>(x, W1, b1, W2, b2, Wo, bo, out, ws);
}

// Round 7
// 8352.412 us; speedup vs baseline: 2.6690x; 1.2458x over previous
//
#include <hip/hip_runtime.h>
#include <math.h>

#define T_ 512

// fp32 fast nonlinearities (reference path is fp32 sigmoid/tanh).
__device__ __forceinline__ float sigf(float x) {
  return __builtin_amdgcn_rcpf(1.0f + __expf(-x));
}
__device__ __forceinline__ float tanhf_(float x) {
  float e = __expf(x + x);                    // inf for large x -> t=1; 0 -> t=-1
  return 1.0f - 2.0f * __builtin_amdgcn_rcpf(e + 1.0f);
}

// Coherent (agent-scope, cache-bypassing) 4-byte load/store for fp32 h exchange.
__device__ __forceinline__ float hloadf(const float* p) {
  unsigned u = __hip_atomic_load((const unsigned*)p,
                                 __ATOMIC_RELAXED, __HIP_MEMORY_SCOPE_AGENT);
  return __builtin_bit_cast(float, u);
}
__device__ __forceinline__ void hstoref(float* p, float v) {
  __hip_atomic_store((unsigned*)p, __builtin_bit_cast(unsigned, v),
                     __ATOMIC_RELAXED, __HIP_MEMORY_SCOPE_AGENT);
}

// A row kc at kc*16 + 4*(kc>>5): 16 fp32 rows (64B), 16B-aligned, +4-float
// stagger per 32-kc block (= one k-team window, so the stagger is constant
// inside a window). Team bases sit at banks {4kt mod 32}: kt and kt+8 share a
// 4-bank window = 2-way = free; og lanes share addresses (broadcast).
__device__ __forceinline__ int aoff16(int kc) { return (kc << 4) + ((kc >> 5) << 2); }

// Grid 256 = 16 groups x 16 blocks, 1 block/CU (R6's 2-block/CU packing failed:
// 2 x 8 waves x 128 VGPR = exactly the 2048-reg pool -> not co-resident ->
// serialized halves). R7 instead halves the L2 weight stream (R4's biggest
// shared sink: 16 MB/XCD/phase = 3.7 us at 4.3 TB/s) by doubling rows/block:
// group g owns batch rows [16g,16g+16); block w owns h-cols [16w,16w+16) of
// both layers -> 256 KB weights/block/phase (8 MB/XCD = 1.85 us), same FMA.
// VGPR budget (hard 128-reg cap, R1/R5 evidence): acc[4][16]=64 + wva/wvb=32.
// GEMM: wave = (layer, gate); lane = (kt 16, og 4); K=32/team; acc[4][16].
// Reduce: R5's verified 4-round recursive halving (60 shuffles), lane ends
// holding row kt / cols og*4..+3 summed over K=512.
__global__ __launch_bounds__(512, 1) void lstm2_head(
    const float* __restrict__ x, const float* __restrict__ W1,
    const float* __restrict__ b1, const float* __restrict__ W2,
    const float* __restrict__ b2, const float* __restrict__ Wo,
    const float* __restrict__ bo, float* __restrict__ out,
    unsigned char* __restrict__ ws)
{
  __shared__ float Alds[12384];  // [kc 768][r 16] + stagger (49.5 KB)
  __shared__ float zbuf[2560];   // [(half,gate,r) 128][16 +4 pad] (10.2 KB)

  const int tid = threadIdx.x;
  const int g  = blockIdx.x >> 4;    // 0..15
  const int w  = blockIdx.x & 15;    // 0..15
  const int rb0 = g << 4;

  unsigned* bar = (unsigned*)ws + (g << 4);            // 64B-spaced counters
  float* hbase = (float*)(ws + 4096);
  float* h1g = hbase + (size_t)g * 8192;               // [2 slots][16 r][256] fp32
  float* h2g = hbase + 131072 + (size_t)g * 8192;

  // Zero both slots of both h arrays (redundant across the group's blocks, benign).
  for (int i = tid; i < 8192; i += 512) { hstoref(h1g + i, 0.0f); hstoref(h2g + i, 0.0f); }

  // group barrier #0 (16 blocks/group)
  __builtin_amdgcn_s_waitcnt(0);
  __syncthreads();
  if (tid == 0) {
    __hip_atomic_fetch_add(bar, 1u, __ATOMIC_RELAXED, __HIP_MEMORY_SCOPE_AGENT);
    while (__hip_atomic_load(bar, __ATOMIC_RELAXED, __HIP_MEMORY_SCOPE_AGENT) < 16u) {}
    __asm__ volatile("" ::: "memory");
  }
  __syncthreads();

  // ---- GEMM mapping ----
  const int lane = tid & 63;
  const int wvid = tid >> 6;               // wave 0..7
  const int half = wvid >> 2;              // 0 = layer1, 1 = layer2
  const int gate = wvid & 3;               // i,j,f,o
  const int kt   = lane >> 2;              // in-wave k-team 0..15 (K=32 each)
  const int og   = lane & 3;               // col-quad within the 16-col slice
  const bool q5 = (lane & 32) != 0;        // kt bit3
  const bool q4 = (lane & 16) != 0;        // kt bit2
  const bool q3 = (lane & 8)  != 0;        // kt bit1
  const bool q2 = (lane & 4)  != 0;        // kt bit0
  const float* Wp = half ? W2 : W1;
  const float* wbase = Wp + (size_t)(kt << 5) * 1024
                          + (gate << 8) + (w << 4) + (og << 2);
  const int abase = aoff16((half << 8) + (kt << 5));
  const int zrow  = ((((half << 2) + gate) << 4) + kt) * 20 + (og << 2);

  // ---- staging mapping: thread = (row sr 16, 8-col group skg 32) ----
  const int sr  = tid & 15;
  const int skg = tid >> 4;
  const int sc0 = skg << 3;

  // ---- update mapping: one cell per thread (512 = 2L x 16r x 16c) ----
  const int L  = tid >> 8;
  const int ur = (tid >> 4) & 15;
  const int uc = tid & 15;
  const float* ubb = L ? b2 : b1;
  const int ucol = (w << 4) + uc;
  const float ub_i = ubb[ucol];
  const float ub_j = ubb[256 + ucol];
  const float ub_f = ubb[512 + ucol] + 1.0f;   // forget bias folded
  const float ub_o = ubb[768 + ucol];
  double cst = 0.0;

  const bool headblk = (w == 0);

  // head: wave v owns rows 2v,2v+1; lane owns h2-cols {lane,64+,128+,192+}.
  // Wo/bo reloaded per call (runs in barrier shadow; saves persistent regs).
  auto do_head = [&](int t3) {
    float wo_r[4][6];
    float bo_r[6];
    #pragma unroll
    for (int q = 0; q < 4; ++q)
      #pragma unroll
      for (int c = 0; c < 6; ++c) wo_r[q][c] = Wo[(lane + (q << 6)) * 6 + c];
    #pragma unroll
    for (int c = 0; c < 6; ++c) bo_r[c] = bo[c];
    #pragma unroll
    for (int rr = 0; rr < 2; ++rr) {
      const int r = (wvid << 1) + rr;
      float pr[6] = {0, 0, 0, 0, 0, 0};
      #pragma unroll
      for (int q = 0; q < 4; ++q) {
        float hv = Alds[aoff16(512 + lane + (q << 6)) + r];
        #pragma unroll
        for (int c = 0; c < 6; ++c) pr[c] = fmaf(hv, wo_r[q][c], pr[c]);
      }
      #pragma unroll
      for (int off = 1; off <= 32; off <<= 1)
        #pragma unroll
        for (int c = 0; c < 6; ++c) pr[c] += __shfl_xor(pr[c], off, 64);
      if (lane == 0) {
        size_t orow = (((size_t)(rb0 + r)) << 9) + (size_t)t3;   // b*T + t
        #pragma unroll
        for (int c = 0; c < 6; ++c) {
          float lg = pr[c] + bo_r[c];
          out[orow * 6 + c] = lg;
          float pd = (lg > 0.0f) ? 1.0f : 0.0f;      // 0.5 < sigmoid <=> lg > 0
          out[(size_t)786432 + orow * 6 + c] = pd;   // condition
          out[(size_t)1572864 + orow * 6 + c] = pd;  // prediction
        }
      }
    }
  };

  // ---- prologue stage for phase 0: x(0), h1(-1)=0 (slot1), h2(-2)=0 (slot0) ----
  {
    const float* xb = x + (size_t)(rb0 + sr) * (T_ * 256) + sc0;   // t=0
    float4 xv0 = *(const float4*)(xb);
    float4 xv1 = *(const float4*)(xb + 4);
    float xs[8] = {xv0.x, xv0.y, xv0.z, xv0.w, xv1.x, xv1.y, xv1.z, xv1.w};
    #pragma unroll
    for (int j = 0; j < 8; ++j) Alds[aoff16(sc0 + j) + sr] = xs[j];
    const float* h1p = h1g + 4096;   // slot 1 (zeroed)
    const float* h2p = h2g;          // slot 0 (zeroed)
    float hv[16];
    #pragma unroll
    for (int j = 0; j < 8; ++j) hv[j]     = hloadf(h1p + (sr << 8) + sc0 + j);
    #pragma unroll
    for (int j = 0; j < 8; ++j) hv[8 + j] = hloadf(h2p + (sr << 8) + sc0 + j);
    #pragma unroll
    for (int j = 0; j < 8; ++j) Alds[aoff16(256 + sc0 + j) + sr] = hv[j];
    #pragma unroll
    for (int j = 0; j < 8; ++j) Alds[aoff16(512 + sc0 + j) + sr] = hv[8 + j];
  }
  __syncthreads();

  // Weights are phase-invariant: first 4-k batch is loop-carried in wva and
  // reloaded each phase inside the barrier shadow (L2 latency hidden).
  float4 wva[4];
  #pragma unroll
  for (int j = 0; j < 4; ++j) wva[j] = *(const float4*)(wbase + (size_t)j * 1024);

  // per-step FMA: 16 rows x 4 cols from one A row (4x float4) and one weight quad
  auto fma16 = [&](float (&acc)[4][16], const float* as, const float4 wv) {
    float4 a0 = *(const float4*)(as);
    float4 a1 = *(const float4*)(as + 4);
    float4 a2 = *(const float4*)(as + 8);
    float4 a3 = *(const float4*)(as + 12);
    float a[16] = {a0.x, a0.y, a0.z, a0.w, a1.x, a1.y, a1.z, a1.w,
                   a2.x, a2.y, a2.z, a2.w, a3.x, a3.y, a3.z, a3.w};
    #pragma unroll
    for (int r = 0; r < 16; ++r) {
      acc[0][r] = fmaf(a[r], wv.x, acc[0][r]);
      acc[1][r] = fmaf(a[r], wv.y, acc[1][r]);
      acc[2][r] = fmaf(a[r], wv.z, acc[2][r]);
      acc[3][r] = fmaf(a[r], wv.w, acc[3][r]);
    }
  };

  // Phase p: layer1(t=p), layer2(t=p-1), head(t=p-2).
  #pragma unroll 1
  for (int p = 0; p <= T_ + 1; ++p) {
    // ---- GEMM: lane covers 4 gate-cols x 16 rows over k in [32kt, 32kt+32).
    // 4+4 float4 ping-pong: 4 steps (= 512 FMA-cycles) of lookahead > L2 lat.
    float acc[4][16];
    #pragma unroll
    for (int c = 0; c < 4; ++c)
      #pragma unroll
      for (int r = 0; r < 16; ++r) acc[c][r] = 0.0f;
    {
      const float* ap = Alds + abase;
      float4 wvb[4];
      #pragma unroll 1
      for (int sg = 0; sg < 4; ++sg) {
        const int s0 = sg << 3;
        #pragma unroll
        for (int j = 0; j < 4; ++j)
          wvb[j] = *(const float4*)(wbase + (size_t)(s0 + 4 + j) * 1024);
        #pragma unroll
        for (int j = 0; j < 4; ++j) fma16(acc, ap + ((s0 + j) << 4), wva[j]);
        if (sg < 3) {
          #pragma unroll
          for (int j = 0; j < 4; ++j)
            wva[j] = *(const float4*)(wbase + (size_t)(s0 + 8 + j) * 1024);
        }
        #pragma unroll
        for (int j = 0; j < 4; ++j) fma16(acc, ap + ((s0 + 4 + j) << 4), wvb[j]);
      }
    }

    // ---- reduce-scatter over 16 k-teams: 4 rounds of recursive halving.
    // Round: keep own half, send the partner's half, add received. After 4
    // rounds lane (kt,og) holds the full sum for row kt, cols og*4..+3.
    float t1[4][8];
    #pragma unroll
    for (int c = 0; c < 4; ++c)
      #pragma unroll
      for (int q = 0; q < 8; ++q) {
        float send = q5 ? acc[c][q] : acc[c][q + 8];
        float keep = q5 ? acc[c][q + 8] : acc[c][q];
        t1[c][q] = keep + __shfl_xor(send, 32, 64);
      }
    float t2[4][4];
    #pragma unroll
    for (int c = 0; c < 4; ++c)
      #pragma unroll
      for (int q = 0; q < 4; ++q) {
        float send = q4 ? t1[c][q] : t1[c][q + 4];
        float keep = q4 ? t1[c][q + 4] : t1[c][q];
        t2[c][q] = keep + __shfl_xor(send, 16, 64);
      }
    float t3[4][2];
    #pragma unroll
    for (int c = 0; c < 4; ++c)
      #pragma unroll
      for (int q = 0; q < 2; ++q) {
        float send = q3 ? t2[c][q] : t2[c][q + 2];
        float keep = q3 ? t2[c][q + 2] : t2[c][q];
        t3[c][q] = keep + __shfl_xor(send, 8, 64);
      }
    {
      float z[4];
      #pragma unroll
      for (int c = 0; c < 4; ++c) {
        float send = q2 ? t3[c][0] : t3[c][1];
        float keep = q2 ? t3[c][1] : t3[c][0];
        z[c] = keep + __shfl_xor(send, 4, 64);
      }
      // stride-20 rows: 16B-aligned float4 store, banks spread (20kt mod 32)
      *(float4*)&zbuf[zrow] = make_float4(z[0], z[1], z[2], z[3]);
    }
    __syncthreads();   // #1: z ready

    // ---- Cell update: fp32 gates (v_exp_f32), fp64 c-state accumulate ----
    {
      const bool uact = L ? (p >= 1 && p <= T_) : (p < T_);
      if (uact) {
        const float* za = zbuf + ((L << 6) + ur) * 20 + uc;   // gate stride 320
        float si = sigf(za[0]   + ub_i);
        float tj = tanhf_(za[320] + ub_j);
        float sf = sigf(za[640] + ub_f);
        float so = sigf(za[960] + ub_o);
        cst = cst * (double)sf + (double)(si * tj);
        float hv = tanhf_((float)cst) * so;
        float* hd = L ? (h2g + (((p + 1) & 1) << 12)) : (h1g + ((p & 1) << 12));
        hstoref(hd + (ur << 8) + ucol, hv);
      }
    }

    if (p <= T_) {
      // head BEFORE the drain: w0's head work hides its own store latency.
      if (headblk && p >= 2) do_head(p - 2);

      __builtin_amdgcn_s_waitcnt(0);
      __syncthreads();   // #2: all waves' h stores drained
      if (tid == 0)
        __hip_atomic_fetch_add(bar, 1u, __ATOMIC_RELAXED, __HIP_MEMORY_SCOPE_AGENT);

      // ---- barrier shadow: x(p+1) prefetch + next-phase weight batch ----
      const int xp1 = (p + 1 < T_) ? (p + 1) : (T_ - 1);
      const float* xb = x + (size_t)(rb0 + sr) * (T_ * 256) + (size_t)xp1 * 256 + sc0;
      float4 xv0 = *(const float4*)(xb);
      float4 xv1 = *(const float4*)(xb + 4);
      float xs[8] = {xv0.x, xv0.y, xv0.z, xv0.w, xv1.x, xv1.y, xv1.z, xv1.w};
      #pragma unroll
      for (int j = 0; j < 8; ++j) Alds[aoff16(sc0 + j) + sr] = xs[j];

      #pragma unroll
      for (int j = 0; j < 4; ++j) wva[j] = *(const float4*)(wbase + (size_t)j * 1024);

      if (tid == 0) {
        const unsigned target = ((unsigned)(p + 2)) << 4;
        while (__hip_atomic_load(bar, __ATOMIC_RELAXED, __HIP_MEMORY_SCOPE_AGENT) < target) {}
        __asm__ volatile("" ::: "memory");
      }
      __syncthreads();   // #3: group h published

      // ---- stage h1(p), h2(p-1) for phase p+1 ----
      const float* h1p = h1g + ((p & 1) << 12);
      const float* h2p = h2g + (((p + 1) & 1) << 12);
      float hv[16];
      #pragma unroll
      for (int j = 0; j < 8; ++j) hv[j]     = hloadf(h1p + (sr << 8) + sc0 + j);
      #pragma unroll
      for (int j = 0; j < 8; ++j) hv[8 + j] = hloadf(h2p + (sr << 8) + sc0 + j);
      #pragma unroll
      for (int j = 0; j < 8; ++j) Alds[aoff16(256 + sc0 + j) + sr] = hv[j];
      #pragma unroll
      for (int j = 0; j < 8; ++j) Alds[aoff16(512 + sc0 + j) + sr] = hv[8 + j];
      __syncthreads();   // #4: A staged for next phase
    } else {
      // final phase: emit last head (t3 = T_-1), no barrier/stage needed
      if (headblk) do_head(p - 2);
    }
  }
}

extern "C" void kernel_launch(void* const* d_in, const int* in_sizes, int n_in,
                              void* d_out, int out_size, void* d_ws, size_t ws_size,
                              hipStream_t stream) {
  const float* x  = (const float*)d_in[0];
  const float* W1 = (const float*)d_in[1];
  const float* b1 = (const float*)d_in[2];
  const float* W2 = (const float*)d_in[3];
  const float* b2 = (const float*)d_in[4];
  const float* Wo = (const float*)d_in[5];
  const float* bo = (const float*)d_in[6];
  float* out = (float*)d_out;
  unsigned char* ws = (unsigned char*)d_ws;

  // Zero barrier counters (first 4 KB of ws); part of the captured graph.
  hipMemsetAsync(d_ws, 0, 4096, stream);

  lstm2_head<<<dim3(256), dim3(512), 0, stream>>>(x, W1, b1, W2, b2, Wo, bo, out, ws);
}